// Round 20
// baseline (147.701 us; speedup 1.0000x reference)
//
#include <hip/hip_runtime.h>
#include <math.h>

#define D 4096
#define NSLOTS 128
#define TR 8192
#define NKQ 8             // split-K ways
#define KCH 512           // K-chunk per block (16 steps of 32)
#define EPS_TRIG 1e-3f    // hi-only score noise: 9-sigma gap guard
#define WIN 5e-4f         // rescore window: 6-sigma single-score guard

typedef __attribute__((ext_vector_type(8))) short bf16x8;
typedef __attribute__((ext_vector_type(4))) float f32x4;

union BV { bf16x8 v; unsigned u[4]; };

__device__ __forceinline__ unsigned short bfrne(float x) {
  unsigned u = __float_as_uint(x);
  unsigned r = u + 0x7fffu + ((u >> 16) & 1u);   // round-to-nearest-even
  return (unsigned short)(r >> 16);
}

// ---- Kernel A: EMA write + ws_mem fp32 + MFh (scores B-frag) + BTF planes ---
// MFh: unit = ks*512 + sg*64 + lane  (scores B operand, k-major)
// BTF: unit = (cg*4 + ks)*64 + fo*16 + fr — gather's B operand in lane order.
__global__ __launch_bounds__(256) void update_mem_kernel(
    const float* __restrict__ values, const float* __restrict__ memory,
    const float* __restrict__ gate_w, const float* __restrict__ gate_b,
    const int* __restrict__ layer_idx_p, const int* __restrict__ ptr_p,
    int T_W, float* __restrict__ ws_mem,
    unsigned short* __restrict__ MFh,
    unsigned short* __restrict__ BTFh, unsigned short* __restrict__ BTFm) {
  const int l = layer_idx_p[0], p = ptr_p[0], s = blockIdx.x, tid = threadIdx.x;
  int t0 = ((s - p) % NSLOTS + NSLOTS) % NSLOTS;
  const bool written = (t0 < T_W);
  const int t = written ? (t0 + ((T_W - 1 - t0) / NSLOTS) * NSLOTS) : 0; // last write wins
  const float* mrow = memory + ((size_t)l * NSLOTS + s) * D;
  const float* vrow = values + (size_t)t * D;

  float acoef = 0.f, bcoef = 1.0f;
  if (written) {
    const float* gw = gate_w + (size_t)l * D;
    double acc = 0.0;
    for (int j = tid; j < D; j += 256)
      acc += (double)vrow[j] * (double)gw[j];
    for (int off = 32; off; off >>= 1) acc += __shfl_down(acc, off, 64);
    __shared__ double wsum[4];
    if ((tid & 63) == 0) wsum[tid >> 6] = acc;
    __syncthreads();
    double dot = wsum[0] + wsum[1] + wsum[2] + wsum[3];
    float x = (float)dot + gate_b[l];
    float g = 1.0f / (1.0f + expf(-x));
    acoef = 0.1f * g; bcoef = 0.9f;
  }

  const int sg = s >> 4, fr_s = s & 15;
  const int ksS = s >> 5, foS = (s >> 3) & 3, posS = s & 7;
  for (int j8 = tid; j8 < D / 8; j8 += 256) {     // 8-float span (cols of slot s)
    float4 mv0 = ((const float4*)mrow)[j8 * 2];
    float4 mv1 = ((const float4*)mrow)[j8 * 2 + 1];
    float4 vv0 = make_float4(0.f, 0.f, 0.f, 0.f), vv1 = vv0;
    if (written) {
      vv0 = ((const float4*)vrow)[j8 * 2];
      vv1 = ((const float4*)vrow)[j8 * 2 + 1];
    }
    float ov[8];
    ov[0] = acoef * vv0.x + bcoef * mv0.x;
    ov[1] = acoef * vv0.y + bcoef * mv0.y;
    ov[2] = acoef * vv0.z + bcoef * mv0.z;
    ov[3] = acoef * vv0.w + bcoef * mv0.w;
    ov[4] = acoef * vv1.x + bcoef * mv1.x;
    ov[5] = acoef * vv1.y + bcoef * mv1.y;
    ov[6] = acoef * vv1.z + bcoef * mv1.z;
    ov[7] = acoef * vv1.w + bcoef * mv1.w;
    ((float4*)(ws_mem + (size_t)s * D))[j8 * 2] =
        make_float4(ov[0], ov[1], ov[2], ov[3]);
    ((float4*)(ws_mem + (size_t)s * D))[j8 * 2 + 1] =
        make_float4(ov[4], ov[5], ov[6], ov[7]);

    unsigned short h[8], md[8];
#pragma unroll
    for (int e = 0; e < 8; ++e) {
      h[e] = bfrne(ov[e]);
      float f = __uint_as_float((unsigned)h[e] << 16);
      md[e] = bfrne(ov[e] - f);
    }
    const int ks = j8 >> 2, fo = j8 & 3;
    const size_t unit = (size_t)ks * 512 + sg * 64 + fo * 16 + fr_s;
    uint4 hp;
    hp.x = (unsigned)h[0] | ((unsigned)h[1] << 16);
    hp.y = (unsigned)h[2] | ((unsigned)h[3] << 16);
    hp.z = (unsigned)h[4] | ((unsigned)h[5] << 16);
    hp.w = (unsigned)h[6] | ((unsigned)h[7] << 16);
    ((uint4*)MFh)[unit] = hp;
#pragma unroll
    for (int e = 0; e < 8; ++e) {
      int c = j8 * 8 + e;
      size_t u = ((size_t)(c >> 4) * 4 + ksS) * 64 + foS * 16 + (c & 15);
      BTFh[u * 8 + posS] = h[e];
      BTFm[u * 8 + posS] = md[e];
    }
  }
}

// ---- Kernel B: partial scores — pure-VGPR streaming, no LDS, no barriers ---
// grid = (TR/64)*NKQ = 1024 blocks x 256 thr. Block (qt,kq): q-rows qt*64..+64,
// K = kq*512..+512, 16 K-steps. Each lane loads its A-fragment DIRECTLY from
// queries (plain loads at full HBM BW — bypasses the global_load_lds path that
// pinned every r8-r19 variant at ~1.3 TB/s). Static reg pipeline: Q dist-2
// (qA[4]), B dist-1 (qB[2], L2-hot fragment-packed). Wave-private, free-run.
__global__ __launch_bounds__(256) void scores_kernel(
    const float* __restrict__ queries, const unsigned short* __restrict__ MFh,
    float* __restrict__ part) {
  const int tid = threadIdx.x, lane = tid & 63, w = tid >> 6;
  const int fr = lane & 15, fo = lane >> 4;
  const int qt = blockIdx.x >> 3, kq = blockIdx.x & (NKQ - 1);
  const int qbase = qt * 64;
  const int kbase = kq * KCH;

  // direct A-fragment pointer: row qbase + w*16 + fr, k-octet fo*8
  const float* qp = queries + (size_t)(qbase + w * 16 + fr) * D + kbase + fo * 8;
  // B: fragment-packed MFh, lane-contiguous 1KB wave loads (L2-hot)
  const unsigned short* bsrc = MFh + (size_t)kq * 16 * 4096 + (size_t)lane * 8;

  f32x4 acc[8];
#pragma unroll
  for (int cg = 0; cg < 8; ++cg) acc[cg] = (f32x4){0.f, 0.f, 0.f, 0.f};

  float4 qA[4][2];    // Q pipeline, distance 2
  bf16x8 qB[2][8];    // B pipeline, distance 1

  // prologue
#pragma unroll
  for (int i = 0; i < 2; ++i) {
    qA[i][0] = *(const float4*)(qp + i * 32);
    qA[i][1] = *(const float4*)(qp + i * 32 + 4);
  }
#pragma unroll
  for (int cg = 0; cg < 8; ++cg)
    qB[0][cg] = *(const bf16x8*)(bsrc + cg * 512);

#pragma unroll
  for (int s = 0; s < 16; ++s) {
    // prefetch (targets disjoint from buffers consumed this iter)
    if (s + 2 < 16) {
      qA[(s + 2) & 3][0] = *(const float4*)(qp + (s + 2) * 32);
      qA[(s + 2) & 3][1] = *(const float4*)(qp + (s + 2) * 32 + 4);
    }
    if (s + 1 < 16) {
#pragma unroll
      for (int cg = 0; cg < 8; ++cg)
        qB[(s + 1) & 1][cg] =
            *(const bf16x8*)(bsrc + (size_t)(s + 1) * 4096 + cg * 512);
    }
    // compute step s
    float4 a0 = qA[s & 3][0], a1 = qA[s & 3][1];
    float qf[8] = {a0.x, a0.y, a0.z, a0.w, a1.x, a1.y, a1.z, a1.w};
    BV ah;
#pragma unroll
    for (int i = 0; i < 4; ++i) {
      unsigned u0 = __float_as_uint(qf[2 * i]);
      unsigned u1 = __float_as_uint(qf[2 * i + 1]);
      ah.u[i] = (u0 >> 16) | (u1 & 0xffff0000u);   // truncated hi
    }
#pragma unroll
    for (int cg = 0; cg < 8; ++cg)
      acc[cg] = __builtin_amdgcn_mfma_f32_16x16x32_bf16(ah.v, qB[s & 1][cg],
                                                        acc[cg], 0, 0, 0);
  }

  float* op = part + ((size_t)kq * TR + qbase) * NSLOTS;
#pragma unroll
  for (int cg = 0; cg < 8; ++cg)
#pragma unroll
    for (int r = 0; r < 4; ++r)
      op[(size_t)(w * 16 + fo * 4 + r) * NSLOTS + cg * 16 + fr] = acc[cg][r];
}

// ---- Kernel C: reduce-partials -> top-k -> softmax -> AF fragment planes ----
__device__ __forceinline__ unsigned mapf(float f) {
  unsigned u = __float_as_uint(f);
  return (u & 0x80000000u) ? ~u : (u | 0x80000000u);
}
__device__ __forceinline__ float unmapf(unsigned u) {
  return __uint_as_float((u & 0x80000000u) ? (u & 0x7fffffffu) : ~u);
}

__device__ __forceinline__ void wave_select(
    float va, float vb, int l, int k, int iters,
    float &m, float &sum, bool &sela, bool &selb, float &vkm1, float &vkk) {
  m = 0.f; sum = 0.f; sela = false; selb = false; vkm1 = 0.f; vkk = -3.4e38f;
  for (int it = 0; it < iters; ++it) {
    unsigned long long ka =
        ((unsigned long long)mapf(va) << 32) | (unsigned)(127 - l);
    unsigned long long kb =
        ((unsigned long long)mapf(vb) << 32) | (unsigned)(63 - l);
    unsigned long long key = ka > kb ? ka : kb;
#pragma unroll
    for (int off = 32; off; off >>= 1) {
      unsigned long long o = __shfl_xor(key, off, 64);
      if (o > key) key = o;
    }
    int idx = 127 - (int)(unsigned)(key & 0xffffffffULL);
    float val = unmapf((unsigned)(key >> 32));
    if (it == 0) m = val;
    if (it < k) sum += expf(val - m);
    if (it == k - 1) vkm1 = val;
    if (it == k) vkk = val;
    if (idx == l) { sela = sela || (it < k); va = -INFINITY; }
    if (idx == l + 64) { selb = selb || (it < k); vb = -INFINITY; }
  }
}

__device__ __forceinline__ float rescore_slot(const float* __restrict__ qrow,
                                              const float* __restrict__ mrow,
                                              int l) {
  double acc = 0.0;
#pragma unroll 4
  for (int c = 0; c < 16; ++c) {
    int j = c * 256 + l * 4;
    float4 qv = *(const float4*)(qrow + j);
    float4 mv = *(const float4*)(mrow + j);
    acc += (double)qv.x * (double)mv.x;
    acc += (double)qv.y * (double)mv.y;
    acc += (double)qv.z * (double)mv.z;
    acc += (double)qv.w * (double)mv.w;
  }
#pragma unroll
  for (int off = 32; off; off >>= 1) acc += __shfl_xor(acc, off, 64);
  return (float)(acc * 0.015625);
}

__global__ __launch_bounds__(256) void topk_kernel(
    const float* __restrict__ part, const float* __restrict__ ws_mem,
    const float* __restrict__ queries, const int* __restrict__ k_p,
    unsigned short* __restrict__ AFh, unsigned short* __restrict__ AFm) {
  const int w = threadIdx.x >> 6, l = threadIdx.x & 63;
  const int row = blockIdx.x * 4 + w;
  int k = k_p[0];
  if (k < 1) k = 1;
  if (k > NSLOTS) k = NSLOTS;
  const int ksel = (k < NSLOTS) ? k + 1 : k;

  float origa = 0.f, origb = 0.f;
#pragma unroll
  for (int kq = 0; kq < NKQ; ++kq) {
    origa += part[((size_t)kq * TR + row) * NSLOTS + l];
    origb += part[((size_t)kq * TR + row) * NSLOTS + 64 + l];
  }
  origa *= 0.015625f;   // 1/sqrt(4096)
  origb *= 0.015625f;

  float m, sum, vkm1, vkk;
  bool sela, selb;
  wave_select(origa, origb, l, k, ksel, m, sum, sela, selb, vkm1, vkk);

  if (ksel > k && (vkm1 - vkk) < EPS_TRIG) {
    // exact fp64 rescore of boundary-window slots (set-membership fix)
    const float* qrow = queries + (size_t)row * D;
    float lo = vkk - WIN, hi = vkm1 + WIN;
    unsigned long long ba = __ballot(origa >= lo && origa <= hi);
    unsigned long long bb = __ballot(origb >= lo && origb <= hi);
    while (ba) {
      int s = __ffsll(ba) - 1; ba &= ba - 1;
      float ex = rescore_slot(qrow, ws_mem + (size_t)s * D, l);
      if (l == s) origa = ex;
    }
    while (bb) {
      int s = __ffsll(bb) - 1; bb &= bb - 1;
      float ex = rescore_slot(qrow, ws_mem + (size_t)(s + 64) * D, l);
      if (l == s) origb = ex;
    }
    wave_select(origa, origb, l, k, k, m, sum, sela, selb, vkm1, vkk);
  }

  const float inv = 1.0f / sum;
  float wa = sela ? expf(origa - m) * inv : 0.f;
  float wb = selb ? expf(origb - m) * inv : 0.f;

  unsigned short ha = bfrne(wa);
  unsigned short ma = bfrne(wa - __uint_as_float((unsigned)ha << 16));
  unsigned short hb = bfrne(wb);
  unsigned short mb = bfrne(wb - __uint_as_float((unsigned)hb << 16));

  // AF fragment layout: unit = (rg*4 + ks)*64 + fo*16 + fr, pos = slot&7
  const int rg = row >> 4, frr = row & 15;
  const size_t ua =
      (((size_t)rg * 4 + (l >> 5)) * 64 + ((l >> 3) & 3) * 16 + frr) * 8 + (l & 7);
  const size_t ub =
      (((size_t)rg * 4 + (l >> 5) + 2) * 64 + ((l >> 3) & 3) * 16 + frr) * 8 + (l & 7);
  AFh[ua] = ha; AFm[ua] = ma;
  AFh[ub] = hb; AFm[ub] = mb;
}

// ---- Kernel D: out = A @ mem^T — fragment-direct, no LDS, no barriers ------
__global__ __launch_bounds__(256) void gather_kernel(
    const unsigned short* __restrict__ AFh, const unsigned short* __restrict__ AFm,
    const unsigned short* __restrict__ BTFh, const unsigned short* __restrict__ BTFm,
    float* __restrict__ out) {
  const int tid = threadIdx.x, lane = tid & 63, w = tid >> 6;
  const int fr = lane & 15, fo = lane >> 4;
  const int rowblk = blockIdx.x >> 5, colblk = blockIdx.x & 31;
  const int r0 = rowblk * 128 + w * 32;
  const int rg0 = r0 >> 4;

  // A fragments: 2 rg x 4 ks x 2 planes (held in regs for the whole block)
  bf16x8 a_h[2][4], a_m[2][4];
#pragma unroll
  for (int rg = 0; rg < 2; ++rg)
#pragma unroll
    for (int ks = 0; ks < 4; ++ks) {
      const size_t u = (((size_t)(rg0 + rg) * 4 + ks) * 64 + lane) * 8;
      a_h[rg][ks] = *(const bf16x8*)(AFh + u);
      a_m[rg][ks] = *(const bf16x8*)(AFm + u);
    }

#pragma unroll 2
  for (int cgi = 0; cgi < 8; ++cgi) {
    const int cg = colblk * 8 + cgi;
    bf16x8 b_h[4], b_m[4];
#pragma unroll
    for (int ks = 0; ks < 4; ++ks) {
      const size_t u = (((size_t)cg * 4 + ks) * 64 + lane) * 8;
      b_h[ks] = *(const bf16x8*)(BTFh + u);
      b_m[ks] = *(const bf16x8*)(BTFm + u);
    }
    const int col = cg * 16 + fr;
#pragma unroll
    for (int rg = 0; rg < 2; ++rg) {
      f32x4 acc = {0.f, 0.f, 0.f, 0.f};
#pragma unroll
      for (int ks = 0; ks < 4; ++ks) {
        acc = __builtin_amdgcn_mfma_f32_16x16x32_bf16(a_m[rg][ks], b_h[ks], acc, 0, 0, 0);
        acc = __builtin_amdgcn_mfma_f32_16x16x32_bf16(a_h[rg][ks], b_m[ks], acc, 0, 0, 0);
        acc = __builtin_amdgcn_mfma_f32_16x16x32_bf16(a_h[rg][ks], b_h[ks], acc, 0, 0, 0);
      }
#pragma unroll
      for (int r = 0; r < 4; ++r)
        out[(size_t)(r0 + rg * 16 + fo * 4 + r) * D + col] = acc[r];
    }
  }
}

extern "C" void kernel_launch(void* const* d_in, const int* in_sizes, int n_in,
                              void* d_out, int out_size, void* d_ws, size_t ws_size,
                              hipStream_t stream) {
  const float* values  = (const float*)d_in[0];
  const float* queries = (const float*)d_in[1];
  const float* memory  = (const float*)d_in[2];
  const float* gate_w  = (const float*)d_in[3];
  const float* gate_b  = (const float*)d_in[4];
  const int* layer_idx = (const int*)d_in[5];
  const int* k_p       = (const int*)d_in[6];
  const int* ptr_p     = (const int*)d_in[7];

  const int T_W = in_sizes[0] / D;   // 128
  const int T_R = in_sizes[1] / D;   // 8192

  float* ws_mem = (float*)d_ws;                              // 2 MiB
  float* part   = ws_mem + (size_t)NSLOTS * D;               // 8 planes, 32 MiB
  unsigned short* MFh  = (unsigned short*)(part + (size_t)NKQ * TR * NSLOTS);
  unsigned short* BTFh = MFh  + (size_t)NSLOTS * D;          // 1 MiB each
  unsigned short* BTFm = BTFh + (size_t)NSLOTS * D;
  unsigned short* AFh  = BTFm + (size_t)NSLOTS * D;          // 2 MiB each
  unsigned short* AFm  = AFh  + (size_t)T_R * NSLOTS;

  update_mem_kernel<<<NSLOTS, 256, 0, stream>>>(
      values, memory, gate_w, gate_b, layer_idx, ptr_p, T_W,
      ws_mem, MFh, BTFh, BTFm);
  scores_kernel<<<(T_R / 64) * NKQ, 256, 0, stream>>>(queries, MFh, part);
  topk_kernel<<<T_R / 4, 256, 0, stream>>>(part, ws_mem, queries, k_p, AFh, AFm);
  gather_kernel<<<(T_R / 128) * (D / 128), 256, 0, stream>>>(AFh, AFm, BTFh, BTFm,
                                                             (float*)d_out);
}

// Round 21
// 132.399 us; speedup vs baseline: 1.1156x; 1.1156x over previous
//
#include <hip/hip_runtime.h>
#include <math.h>

#define D 4096
#define NSLOTS 128
#define TR 8192
#define NKQ 4             // split-K ways (halved: part round-trip 32->16 MiB)
#define KCH 1024          // K-chunk per block (32 steps of 32)
#define EPS_TRIG 1e-3f    // hi-only score noise: 9-sigma gap guard
#define WIN 5e-4f         // rescore window: 6-sigma single-score guard

typedef __attribute__((ext_vector_type(8))) short bf16x8;
typedef __attribute__((ext_vector_type(4))) float f32x4;

union BV { bf16x8 v; unsigned u[4]; };

__device__ __forceinline__ unsigned short bfrne(float x) {
  unsigned u = __float_as_uint(x);
  unsigned r = u + 0x7fffu + ((u >> 16) & 1u);   // round-to-nearest-even
  return (unsigned short)(r >> 16);
}

__device__ __forceinline__ void gload16(const void* gsrc, void* ldst) {
  __builtin_amdgcn_global_load_lds(
      (const __attribute__((address_space(1))) void*)gsrc,
      (__attribute__((address_space(3))) void*)ldst, 16, 0, 0);
}

// ---- Kernel A: EMA write + ws_mem fp32 + MFh (scores B-frag) + BTF planes ---
// MFh: unit = ks*512 + sg*64 + lane  (scores B operand, k-major)
// BTF: unit = (cg*4 + ks)*64 + fo*16 + fr — gather's B operand in lane order.
__global__ __launch_bounds__(256) void update_mem_kernel(
    const float* __restrict__ values, const float* __restrict__ memory,
    const float* __restrict__ gate_w, const float* __restrict__ gate_b,
    const int* __restrict__ layer_idx_p, const int* __restrict__ ptr_p,
    int T_W, float* __restrict__ ws_mem,
    unsigned short* __restrict__ MFh,
    unsigned short* __restrict__ BTFh, unsigned short* __restrict__ BTFm) {
  const int l = layer_idx_p[0], p = ptr_p[0], s = blockIdx.x, tid = threadIdx.x;
  int t0 = ((s - p) % NSLOTS + NSLOTS) % NSLOTS;
  const bool written = (t0 < T_W);
  const int t = written ? (t0 + ((T_W - 1 - t0) / NSLOTS) * NSLOTS) : 0; // last write wins
  const float* mrow = memory + ((size_t)l * NSLOTS + s) * D;
  const float* vrow = values + (size_t)t * D;

  float acoef = 0.f, bcoef = 1.0f;
  if (written) {
    const float* gw = gate_w + (size_t)l * D;
    double acc = 0.0;
    for (int j = tid; j < D; j += 256)
      acc += (double)vrow[j] * (double)gw[j];
    for (int off = 32; off; off >>= 1) acc += __shfl_down(acc, off, 64);
    __shared__ double wsum[4];
    if ((tid & 63) == 0) wsum[tid >> 6] = acc;
    __syncthreads();
    double dot = wsum[0] + wsum[1] + wsum[2] + wsum[3];
    float x = (float)dot + gate_b[l];
    float g = 1.0f / (1.0f + expf(-x));
    acoef = 0.1f * g; bcoef = 0.9f;
  }

  const int sg = s >> 4, fr_s = s & 15;
  const int ksS = s >> 5, foS = (s >> 3) & 3, posS = s & 7;
  for (int j8 = tid; j8 < D / 8; j8 += 256) {     // 8-float span (cols of slot s)
    float4 mv0 = ((const float4*)mrow)[j8 * 2];
    float4 mv1 = ((const float4*)mrow)[j8 * 2 + 1];
    float4 vv0 = make_float4(0.f, 0.f, 0.f, 0.f), vv1 = vv0;
    if (written) {
      vv0 = ((const float4*)vrow)[j8 * 2];
      vv1 = ((const float4*)vrow)[j8 * 2 + 1];
    }
    float ov[8];
    ov[0] = acoef * vv0.x + bcoef * mv0.x;
    ov[1] = acoef * vv0.y + bcoef * mv0.y;
    ov[2] = acoef * vv0.z + bcoef * mv0.z;
    ov[3] = acoef * vv0.w + bcoef * mv0.w;
    ov[4] = acoef * vv1.x + bcoef * mv1.x;
    ov[5] = acoef * vv1.y + bcoef * mv1.y;
    ov[6] = acoef * vv1.z + bcoef * mv1.z;
    ov[7] = acoef * vv1.w + bcoef * mv1.w;
    ((float4*)(ws_mem + (size_t)s * D))[j8 * 2] =
        make_float4(ov[0], ov[1], ov[2], ov[3]);
    ((float4*)(ws_mem + (size_t)s * D))[j8 * 2 + 1] =
        make_float4(ov[4], ov[5], ov[6], ov[7]);

    unsigned short h[8], md[8];
#pragma unroll
    for (int e = 0; e < 8; ++e) {
      h[e] = bfrne(ov[e]);
      float f = __uint_as_float((unsigned)h[e] << 16);
      md[e] = bfrne(ov[e] - f);
    }
    const int ks = j8 >> 2, fo = j8 & 3;
    const size_t unit = (size_t)ks * 512 + sg * 64 + fo * 16 + fr_s;
    uint4 hp;
    hp.x = (unsigned)h[0] | ((unsigned)h[1] << 16);
    hp.y = (unsigned)h[2] | ((unsigned)h[3] << 16);
    hp.z = (unsigned)h[4] | ((unsigned)h[5] << 16);
    hp.w = (unsigned)h[6] | ((unsigned)h[7] << 16);
    ((uint4*)MFh)[unit] = hp;
#pragma unroll
    for (int e = 0; e < 8; ++e) {
      int c = j8 * 8 + e;
      size_t u = ((size_t)(c >> 4) * 4 + ksS) * 64 + foS * 16 + (c & 15);
      BTFh[u * 8 + posS] = h[e];
      BTFm[u * 8 + posS] = md[e];
    }
  }
}

// ---- Kernel B: partial scores, all-DMA staged, counted-vmcnt pipeline ------
// grid = (TR/64) * NKQ = 512 blocks x 256 thr, 64 KB LDS (2 blocks/CU).
// Block (qt,kq): q-rows qt*64..+64, K = kq*1024..+1024, BK=32, 32 steps.
// Both Q (8KB) and B-frag (8KB) DMA-staged into 4 LDS buffers; prefetch
// distance 2; per-iter: STG(s+2) -> vmcnt(8) -> s_barrier -> ds_read+MFMA.
__global__ __launch_bounds__(256) void scores_kernel(
    const float* __restrict__ queries, const unsigned short* __restrict__ MFh,
    float* __restrict__ part) {
  __shared__ float Qs[4][2048];            // 4 x 8 KB
  __shared__ unsigned short Bs[4][4096];   // 4 x 8 KB  => 64 KB total

  const int tid = threadIdx.x, lane = tid & 63, w = tid >> 6;
  const int fr = lane & 15, fo = lane >> 4;
  const int qt = blockIdx.x >> 2, kq = blockIdx.x & (NKQ - 1);
  const int qbase = qt * 64;
  const int kbase = kq * KCH;

  // Q staging: instr i (dl=w*2+i) covers rows 8dl..8dl+8 x 128B, XOR-preswizzled
  const int rl = lane >> 3, ul = lane & 7;
  const int su = ul ^ rl;                   // row&7 == rl
  const float* qsrc[2];
#pragma unroll
  for (int i = 0; i < 2; ++i) {
    int dl = w * 2 + i;
    qsrc[i] = queries + (size_t)(qbase + 8 * dl + rl) * D + kbase + su * 4;
  }
  // B staging: lane-contiguous from fragment-packed MFh
  const unsigned short* bsrc = MFh + (size_t)kq * 32 * 4096 + (size_t)lane * 8;

  f32x4 acc[8];
#pragma unroll
  for (int cg = 0; cg < 8; ++cg) acc[cg] = (f32x4){0.f, 0.f, 0.f, 0.f};

  const int rowA = w * 16 + fr;

#define STG(B_, S_) do {                                                     \
    const int k0_ = (S_) * 32;                                               \
    _Pragma("unroll")                                                        \
    for (int i = 0; i < 2; ++i)                                              \
      gload16(qsrc[i] + k0_, &Qs[B_][(w * 2 + i) * 256]);                    \
    _Pragma("unroll")                                                        \
    for (int i = 0; i < 2; ++i)                                              \
      gload16(bsrc + (size_t)(S_) * 4096 + (w * 2 + i) * 512,                \
              &Bs[B_][(w * 2 + i) * 512]);                                   \
  } while (0)

#define CMP(B_) do {                                                         \
    bf16x8 bh_[8];                                                           \
    _Pragma("unroll")                                                        \
    for (int cg = 0; cg < 8; ++cg)                                           \
      bh_[cg] = *(const bf16x8*)&Bs[B_][(cg * 64 + lane) * 8];               \
    float4 a0 = *(const float4*)&Qs[B_][rowA * 32 + (((fo * 2) ^ (rowA & 7)) << 2)]; \
    float4 a1 = *(const float4*)&Qs[B_][rowA * 32 + ((((fo * 2) | 1) ^ (rowA & 7)) << 2)]; \
    float qf[8] = {a0.x, a0.y, a0.z, a0.w, a1.x, a1.y, a1.z, a1.w};          \
    BV ah;                                                                   \
    _Pragma("unroll")                                                        \
    for (int i = 0; i < 4; ++i) {                                            \
      unsigned u0 = __float_as_uint(qf[2 * i]);                              \
      unsigned u1 = __float_as_uint(qf[2 * i + 1]);                          \
      ah.u[i] = (u0 >> 16) | (u1 & 0xffff0000u);   /* truncated hi */        \
    }                                                                        \
    _Pragma("unroll")                                                        \
    for (int cg = 0; cg < 8; ++cg)                                           \
      acc[cg] = __builtin_amdgcn_mfma_f32_16x16x32_bf16(ah.v, bh_[cg], acc[cg], 0, 0, 0); \
  } while (0)

  STG(0, 0);                       // 4 DMA
  STG(1, 1);                       // 8 DMA outstanding
#pragma unroll
  for (int s = 0; s < 32; ++s) {
    if (s + 2 < 32) STG((s + 2) & 3, s + 2);
    // wait for step-s DMA: newer ops = (s+1)'s 4 + (s+2)'s 4 = 8 (tail: 4, 0)
    if (s <= 29)      asm volatile("s_waitcnt vmcnt(8)" ::: "memory");
    else if (s == 30) asm volatile("s_waitcnt vmcnt(4)" ::: "memory");
    else              asm volatile("s_waitcnt vmcnt(0)" ::: "memory");
    __builtin_amdgcn_sched_barrier(0);
    __builtin_amdgcn_s_barrier();   // all waves' step-s data now in LDS
    CMP(s & 3);
  }
#undef STG
#undef CMP

  float* op = part + ((size_t)kq * TR + qbase) * NSLOTS;
#pragma unroll
  for (int cg = 0; cg < 8; ++cg)
#pragma unroll
    for (int r = 0; r < 4; ++r)
      op[(size_t)(w * 16 + fo * 4 + r) * NSLOTS + cg * 16 + fr] = acc[cg][r];
}

// ---- Kernel C: reduce-partials -> top-k -> softmax -> AF fragment planes ----
__device__ __forceinline__ unsigned mapf(float f) {
  unsigned u = __float_as_uint(f);
  return (u & 0x80000000u) ? ~u : (u | 0x80000000u);
}
__device__ __forceinline__ float unmapf(unsigned u) {
  return __uint_as_float((u & 0x80000000u) ? (u & 0x7fffffffu) : ~u);
}

__device__ __forceinline__ void wave_select(
    float va, float vb, int l, int k, int iters,
    float &m, float &sum, bool &sela, bool &selb, float &vkm1, float &vkk) {
  m = 0.f; sum = 0.f; sela = false; selb = false; vkm1 = 0.f; vkk = -3.4e38f;
  for (int it = 0; it < iters; ++it) {
    unsigned long long ka =
        ((unsigned long long)mapf(va) << 32) | (unsigned)(127 - l);
    unsigned long long kb =
        ((unsigned long long)mapf(vb) << 32) | (unsigned)(63 - l);
    unsigned long long key = ka > kb ? ka : kb;
#pragma unroll
    for (int off = 32; off; off >>= 1) {
      unsigned long long o = __shfl_xor(key, off, 64);
      if (o > key) key = o;
    }
    int idx = 127 - (int)(unsigned)(key & 0xffffffffULL);
    float val = unmapf((unsigned)(key >> 32));
    if (it == 0) m = val;
    if (it < k) sum += expf(val - m);
    if (it == k - 1) vkm1 = val;
    if (it == k) vkk = val;
    if (idx == l) { sela = sela || (it < k); va = -INFINITY; }
    if (idx == l + 64) { selb = selb || (it < k); vb = -INFINITY; }
  }
}

__device__ __forceinline__ float rescore_slot(const float* __restrict__ qrow,
                                              const float* __restrict__ mrow,
                                              int l) {
  double acc = 0.0;
#pragma unroll 4
  for (int c = 0; c < 16; ++c) {
    int j = c * 256 + l * 4;
    float4 qv = *(const float4*)(qrow + j);
    float4 mv = *(const float4*)(mrow + j);
    acc += (double)qv.x * (double)mv.x;
    acc += (double)qv.y * (double)mv.y;
    acc += (double)qv.z * (double)mv.z;
    acc += (double)qv.w * (double)mv.w;
  }
#pragma unroll
  for (int off = 32; off; off >>= 1) acc += __shfl_xor(acc, off, 64);
  return (float)(acc * 0.015625);
}

__global__ __launch_bounds__(256) void topk_kernel(
    const float* __restrict__ part, const float* __restrict__ ws_mem,
    const float* __restrict__ queries, const int* __restrict__ k_p,
    unsigned short* __restrict__ AFh, unsigned short* __restrict__ AFm) {
  const int w = threadIdx.x >> 6, l = threadIdx.x & 63;
  const int row = blockIdx.x * 4 + w;
  int k = k_p[0];
  if (k < 1) k = 1;
  if (k > NSLOTS) k = NSLOTS;
  const int ksel = (k < NSLOTS) ? k + 1 : k;

  float origa = 0.f, origb = 0.f;
#pragma unroll
  for (int kq = 0; kq < NKQ; ++kq) {
    origa += part[((size_t)kq * TR + row) * NSLOTS + l];
    origb += part[((size_t)kq * TR + row) * NSLOTS + 64 + l];
  }
  origa *= 0.015625f;   // 1/sqrt(4096)
  origb *= 0.015625f;

  float m, sum, vkm1, vkk;
  bool sela, selb;
  wave_select(origa, origb, l, k, ksel, m, sum, sela, selb, vkm1, vkk);

  if (ksel > k && (vkm1 - vkk) < EPS_TRIG) {
    // exact fp64 rescore of boundary-window slots (set-membership fix)
    const float* qrow = queries + (size_t)row * D;
    float lo = vkk - WIN, hi = vkm1 + WIN;
    unsigned long long ba = __ballot(origa >= lo && origa <= hi);
    unsigned long long bb = __ballot(origb >= lo && origb <= hi);
    while (ba) {
      int s = __ffsll(ba) - 1; ba &= ba - 1;
      float ex = rescore_slot(qrow, ws_mem + (size_t)s * D, l);
      if (l == s) origa = ex;
    }
    while (bb) {
      int s = __ffsll(bb) - 1; bb &= bb - 1;
      float ex = rescore_slot(qrow, ws_mem + (size_t)(s + 64) * D, l);
      if (l == s) origb = ex;
    }
    wave_select(origa, origb, l, k, k, m, sum, sela, selb, vkm1, vkk);
  }

  const float inv = 1.0f / sum;
  float wa = sela ? expf(origa - m) * inv : 0.f;
  float wb = selb ? expf(origb - m) * inv : 0.f;

  unsigned short ha = bfrne(wa);
  unsigned short ma = bfrne(wa - __uint_as_float((unsigned)ha << 16));
  unsigned short hb = bfrne(wb);
  unsigned short mb = bfrne(wb - __uint_as_float((unsigned)hb << 16));

  // AF fragment layout: unit = (rg*4 + ks)*64 + fo*16 + fr, pos = slot&7
  const int rg = row >> 4, frr = row & 15;
  const size_t ua =
      (((size_t)rg * 4 + (l >> 5)) * 64 + ((l >> 3) & 3) * 16 + frr) * 8 + (l & 7);
  const size_t ub =
      (((size_t)rg * 4 + (l >> 5) + 2) * 64 + ((l >> 3) & 3) * 16 + frr) * 8 + (l & 7);
  AFh[ua] = ha; AFm[ua] = ma;
  AFh[ub] = hb; AFm[ub] = mb;
}

// ---- Kernel D: out = A @ mem^T — fragment-direct, no LDS, no barriers ------
__global__ __launch_bounds__(256) void gather_kernel(
    const unsigned short* __restrict__ AFh, const unsigned short* __restrict__ AFm,
    const unsigned short* __restrict__ BTFh, const unsigned short* __restrict__ BTFm,
    float* __restrict__ out) {
  const int tid = threadIdx.x, lane = tid & 63, w = tid >> 6;
  const int fr = lane & 15, fo = lane >> 4;
  const int rowblk = blockIdx.x >> 5, colblk = blockIdx.x & 31;
  const int r0 = rowblk * 128 + w * 32;
  const int rg0 = r0 >> 4;

  // A fragments: 2 rg x 4 ks x 2 planes (held in regs for the whole block)
  bf16x8 a_h[2][4], a_m[2][4];
#pragma unroll
  for (int rg = 0; rg < 2; ++rg)
#pragma unroll
    for (int ks = 0; ks < 4; ++ks) {
      const size_t u = (((size_t)(rg0 + rg) * 4 + ks) * 64 + lane) * 8;
      a_h[rg][ks] = *(const bf16x8*)(AFh + u);
      a_m[rg][ks] = *(const bf16x8*)(AFm + u);
    }

#pragma unroll 2
  for (int cgi = 0; cgi < 8; ++cgi) {
    const int cg = colblk * 8 + cgi;
    bf16x8 b_h[4], b_m[4];
#pragma unroll
    for (int ks = 0; ks < 4; ++ks) {
      const size_t u = (((size_t)cg * 4 + ks) * 64 + lane) * 8;
      b_h[ks] = *(const bf16x8*)(BTFh + u);
      b_m[ks] = *(const bf16x8*)(BTFm + u);
    }
    const int col = cg * 16 + fr;
#pragma unroll
    for (int rg = 0; rg < 2; ++rg) {
      f32x4 acc = {0.f, 0.f, 0.f, 0.f};
#pragma unroll
      for (int ks = 0; ks < 4; ++ks) {
        acc = __builtin_amdgcn_mfma_f32_16x16x32_bf16(a_m[rg][ks], b_h[ks], acc, 0, 0, 0);
        acc = __builtin_amdgcn_mfma_f32_16x16x32_bf16(a_h[rg][ks], b_m[ks], acc, 0, 0, 0);
        acc = __builtin_amdgcn_mfma_f32_16x16x32_bf16(a_h[rg][ks], b_h[ks], acc, 0, 0, 0);
      }
#pragma unroll
      for (int r = 0; r < 4; ++r)
        out[(size_t)(r0 + rg * 16 + fo * 4 + r) * D + col] = acc[r];
    }
  }
}

extern "C" void kernel_launch(void* const* d_in, const int* in_sizes, int n_in,
                              void* d_out, int out_size, void* d_ws, size_t ws_size,
                              hipStream_t stream) {
  const float* values  = (const float*)d_in[0];
  const float* queries = (const float*)d_in[1];
  const float* memory  = (const float*)d_in[2];
  const float* gate_w  = (const float*)d_in[3];
  const float* gate_b  = (const float*)d_in[4];
  const int* layer_idx = (const int*)d_in[5];
  const int* k_p       = (const int*)d_in[6];
  const int* ptr_p     = (const int*)d_in[7];

  const int T_W = in_sizes[0] / D;   // 128
  const int T_R = in_sizes[1] / D;   // 8192

  float* ws_mem = (float*)d_ws;                              // 2 MiB
  float* part   = ws_mem + (size_t)NSLOTS * D;               // 4 planes, 16 MiB
  unsigned short* MFh  = (unsigned short*)(part + (size_t)NKQ * TR * NSLOTS);
  unsigned short* BTFh = MFh  + (size_t)NSLOTS * D;          // 1 MiB each
  unsigned short* BTFm = BTFh + (size_t)NSLOTS * D;
  unsigned short* AFh  = BTFm + (size_t)NSLOTS * D;          // 2 MiB each
  unsigned short* AFm  = AFh  + (size_t)T_R * NSLOTS;

  update_mem_kernel<<<NSLOTS, 256, 0, stream>>>(
      values, memory, gate_w, gate_b, layer_idx, ptr_p, T_W,
      ws_mem, MFh, BTFh, BTFm);
  scores_kernel<<<(T_R / 64) * NKQ, 256, 0, stream>>>(queries, MFh, part);
  topk_kernel<<<T_R / 4, 256, 0, stream>>>(part, ws_mem, queries, k_p, AFh, AFm);
  gather_kernel<<<(T_R / 128) * (D / 128), 256, 0, stream>>>(AFh, AFm, BTFh, BTFm,
                                                             (float*)d_out);
}